// Round 17
// baseline (79.885 us; speedup 1.0000x reference)
//
#include <hip/hip_runtime.h>
#include <math.h>

#define B_ 64
#define L_ 512
#define N_ 321
#define P_ 720
#define E_ 8
#define R_ 32
#define CID_ 32
#define H_ 64
#define ER_ 256
#define KB2 288      // ER_ + 8 bias-rank + 1 mean + 23 zero-pad
#define HGROWS 384
#define TRS 338      // prepx2 LDS row stride (u16): 169 dw -> 4-way max on reads

typedef __attribute__((ext_vector_type(8))) short bf16x8;
typedef __attribute__((ext_vector_type(4))) float f32x4;
typedef __attribute__((ext_vector_type(8))) unsigned short u16x8;
typedef __attribute__((ext_vector_type(4))) unsigned short u16x4;
typedef __attribute__((ext_vector_type(2))) unsigned short u16x2;

// workspace layout (float offsets)
#define OFF_GATE 0                        // 2568
#define OFF_CS1  2568                     // 256
#define OFF_W1K  2824                     // bf16 256*512 = 65536 f
#define OFF_W2X  68360                    // bf16 720*288 = 103680 f
#define OFF_XT   172040                   // bf16 64*384*512 = 6291456 f
#define OFF_HG   6463496                  // bf16 64*384*288 = 3538944 f
// total ~40 MB

__device__ __forceinline__ unsigned short f2bf(float f) {
    unsigned u = __float_as_uint(f);
    u += 0x7fffu + ((u >> 16) & 1u);
    return (unsigned short)(u >> 16);
}
__device__ __forceinline__ float bf2f(unsigned short h) {
    return __uint_as_float(((unsigned)h) << 16);
}

// ---------------- prep: w1k, w2x, cs1, router (merged) ----------------------
__global__ void prep_kernel(const float* __restrict__ w1, const float* __restrict__ w2,
                            const float* __restrict__ bias,
                            const float* __restrict__ ident,
                            const float* __restrict__ rw1, const float* __restrict__ rb1,
                            const float* __restrict__ rw2, const float* __restrict__ rb2,
                            unsigned short* __restrict__ w1k, unsigned short* __restrict__ w2x,
                            float* __restrict__ cs1, float* __restrict__ gate) {
    __shared__ float red[16][32];
    __shared__ float hid[H_];
    __shared__ float lg[E_];
    int bid = blockIdx.x, t = threadIdx.x;
    if (bid < 128) {                  // w1k [er][l]
        #pragma unroll
        for (int r = 0; r < 2; ++r) {
            int g = bid*1024 + r*512 + t;
            int er = g >> 9, l = g & 511;
            w1k[g] = f2bf(w1[(size_t)(er >> 5)*(L_*R_) + (size_t)l*R_ + (er & 31)]);
        }
    } else if (bid < 848) {           // w2x row p: K-extended
        int p = bid - 128;
        if (t < KB2) {
            unsigned short v;
            if (t < ER_)            v = f2bf(w2[(size_t)t*P_ + p]);
            else if (t < ER_ + E_)  v = f2bf(bias[(size_t)(t - ER_)*P_ + p]);
            else if (t == ER_ + E_) v = 0x3f80;
            else                    v = 0;
            w2x[(size_t)p*KB2 + t] = v;
        }
    } else if (bid < 856) {           // cs1
        int e = bid - 848;
        int q = t >> 5, r = t & 31;
        float s = 0.f;
        for (int l = q; l < L_; l += 16)
            s += bf2f(f2bf(w1[(size_t)e*(L_*R_) + (size_t)l*R_ + r]));
        red[q][r] = s;
        __syncthreads();
        if (q == 0) {
            #pragma unroll
            for (int qq = 1; qq < 16; ++qq) s += red[qq][r];
            cs1[e*32 + r] = s;
        }
    } else {                          // router
        int n = bid - 856;
        if (t < H_) {
            float acc = rb1[t];
            #pragma unroll
            for (int c = 0; c < CID_; ++c)
                acc = fmaf(ident[n*CID_ + c], rw1[c*H_ + t], acc);
            hid[t] = fmaxf(acc, 0.f);
        }
        __syncthreads();
        if (t < E_) {
            float a = rb2[t];
            #pragma unroll
            for (int h = 0; h < H_; ++h) a = fmaf(hid[h], rw2[h*E_ + t], a);
            lg[t] = a;
        }
        __syncthreads();
        if (t == 0) {
            float m = lg[0];
            #pragma unroll
            for (int e = 1; e < E_; ++e) m = fmaxf(m, lg[e]);
            float s = 0.f, ex[E_];
            #pragma unroll
            for (int e = 0; e < E_; ++e) { ex[e] = expf(lg[e] - m); s += ex[e]; }
            float inv = 1.f / s;
            #pragma unroll
            for (int e = 0; e < E_; ++e) gate[n*E_ + e] = ex[e] * inv;
        }
    }
}

// ---------------- prepx2: full-row x reads -> xT[b][n][k] bf16 --------------
// grid 512 = 64 b * 8 kc. Reads 64 FULL rows (82KB sequential), LDS [k][n]
// transpose, writes xT as 8-row x 128B full-line runs. Zero-fills n>=336.
__global__ __launch_bounds__(512) void prepx2_kernel(
        const float* __restrict__ x, unsigned short* __restrict__ xT) {
    __shared__ unsigned short tr[64 * TRS];     // 43264 B
    const int bid = blockIdx.x;
    const int b   = bid >> 3;
    const int kc  = bid & 7;
    const int tid = threadIdx.x;
    const int lane = tid & 63;
    const int wave = tid >> 6;

    const float* xb = x + (size_t)b*L_*N_ + (size_t)kc*64*N_;
    // read: wave w -> rows w*8..w*8+7, full rows, lane-contiguous
    #pragma unroll
    for (int rr = 0; rr < 8; ++rr) {
        const int r = wave*8 + rr;
        const float* row = xb + (size_t)r*N_;
        #pragma unroll
        for (int it = 0; it < 6; ++it) {
            int c = it*64 + lane;
            if (c < N_)        tr[r*TRS + c] = f2bf(row[c]);
            else if (c < 336)  tr[r*TRS + c] = 0;
        }
    }
    __syncthreads();

    // assemble xT rows: thread (n_loc = t>>3, chunk = t&7), 6 passes of 64 n
    #pragma unroll
    for (int pass = 0; pass < 6; ++pass) {
        int n = pass*64 + (tid >> 3);
        int chunk = tid & 7;
        if (n < 336) {
            u16x8 pk;
            #pragma unroll
            for (int j = 0; j < 8; ++j) pk[j] = tr[(chunk*8 + j)*TRS + n];
            *(u16x8*)&xT[((size_t)b*HGROWS + n)*L_ + kc*64 + chunk*8] = pk;
        }
    }
    // zero-fill pad rows 336..383 (keeps NaN out of gemm1xT's junk lanes)
    if (tid < 384) {
        int n = 336 + (tid >> 3);
        int chunk = tid & 7;
        u16x8 z = {0,0,0,0,0,0,0,0};
        *(u16x8*)&xT[((size_t)b*HGROWS + n)*L_ + kc*64 + chunk*8] = z;
    }
}

// ---------------- GEMM1xT: BM=256er, BN=32n, K=512, stage-once --------------
// grid 704 = 8 xcd * (8 b * 11 nt), 512 thr. Stage 32 KB k-contiguous xT tile
// + fused bf16 stats; 16-step MFMA (A = w1k L2-stream ring, B = LDS);
// epilogue gate*(acc - mean*cs1) + K-ext.
__global__ __launch_bounds__(512, 4) void gemm1_kernel(
        const unsigned short* __restrict__ xT, const unsigned short* __restrict__ w1k,
        const float* __restrict__ gate, const float* __restrict__ cs1,
        unsigned short* __restrict__ hg) {
    __shared__ __align__(16) unsigned short xL[32 * 512];   // 32768 B, swizzled
    __shared__ float meanS[32], sdS[32];

    const int bid = blockIdx.x;
    const int xcd = bid & 7;
    const int idx = bid >> 3;            // 0..87
    const int b   = (xcd << 3) + idx / 11;
    const int n0  = (idx % 11) * 32;

    const int tid  = threadIdx.x;
    const int lane = tid & 63;
    const int wave = tid >> 6;          // 0..7
    const int l15  = lane & 15;
    const int kgrp = lane >> 4;         // 0..3

    // ---- stage + stats: thread (n_loc = t>>4, seg = t&15), 64B each ----
    const int n_loc = tid >> 4;          // 0..31
    const int seg   = tid & 15;
    const unsigned short* xrow = xT + ((size_t)b*HGROWS + n0 + n_loc)*L_ + seg*32;
    float s1 = 0.f, s2 = 0.f;
    {
        u16x8 st[4];
        #pragma unroll
        for (int j = 0; j < 4; ++j) {
            st[j] = *(const u16x8*)&xrow[j*8];
            #pragma unroll
            for (int q = 0; q < 8; ++q) {
                float f = bf2f(st[j][q]);
                s1 += f; s2 = fmaf(f, f, s2);
            }
        }
        const int swzw = (n_loc & 7) << 4;
        char* dst = (char*)xL + n_loc*1024;
        #pragma unroll
        for (int j = 0; j < 4; ++j)
            *(u16x8*)(dst + ((seg*64 + j*16) ^ swzw)) = st[j];
    }
    __syncthreads();
    #pragma unroll
    for (int m = 1; m <= 8; m <<= 1) {
        s1 += __shfl_xor(s1, m);
        s2 += __shfl_xor(s2, m);
    }
    if (seg == 0) {
        float mean = s1 * (1.f/L_);
        float var = (s2 - (float)L_*mean*mean) * (1.f/(L_-1));
        meanS[n_loc] = mean;
        sdS[n_loc]   = sqrtf(fmaxf(var, 0.f)) + 1e-6f;
    }
    __syncthreads();

    // ---- MFMA: wave owns er rows wave*32..+32, K=512 (16 steps) ----
    const unsigned short* apA = w1k + (size_t)(wave*32 + l15)*L_;
    const unsigned short* apB = w1k + (size_t)(wave*32 + 16 + l15)*L_;
    const int rsw = (l15 & 7) << 4;     // (16+l15)&7 == l15&7: same for both fn

    f32x4 acc[2][2];
    #pragma unroll
    for (int i = 0; i < 2; ++i)
        #pragma unroll
        for (int j = 0; j < 2; ++j) acc[i][j] = (f32x4){0.f,0.f,0.f,0.f};

    bf16x8 af[4][2];
#define LDA(s_, kk_) { af[s_][0] = *(const bf16x8*)&apA[(kk_)*32 + kgrp*8];      \
                       af[s_][1] = *(const bf16x8*)&apB[(kk_)*32 + kgrp*8]; }
    LDA(0, 0); LDA(1, 1);
    #pragma unroll
    for (int ks = 0; ks < 16; ++ks) {
        if (ks + 2 < 16) LDA((ks + 2) & 3, ks + 2);
        const int cb = (ks*64 + kgrp*16);
        bf16x8 b0 = *(const bf16x8*)((char*)xL + l15*1024        + (cb ^ rsw));
        bf16x8 b1 = *(const bf16x8*)((char*)xL + (16 + l15)*1024 + (cb ^ rsw));
        acc[0][0] = __builtin_amdgcn_mfma_f32_16x16x32_bf16(af[ks & 3][0], b0, acc[0][0], 0, 0, 0);
        acc[0][1] = __builtin_amdgcn_mfma_f32_16x16x32_bf16(af[ks & 3][0], b1, acc[0][1], 0, 0, 0);
        acc[1][0] = __builtin_amdgcn_mfma_f32_16x16x32_bf16(af[ks & 3][1], b0, acc[1][0], 0, 0, 0);
        acc[1][1] = __builtin_amdgcn_mfma_f32_16x16x32_bf16(af[ks & 3][1], b1, acc[1][1], 0, 0, 0);
    }
#undef LDA

    // ---- epilogue: hg[b][n0+nl][er] = gate*(acc - mean*cs1), + K-ext ----
    unsigned short* hgb = hg + ((size_t)b * HGROWS + n0) * KB2;
    #pragma unroll
    for (int fm = 0; fm < 2; ++fm) {
        int er0 = wave*32 + fm*16 + kgrp*4;
        int e = er0 >> 5;
        f32x4 c4 = *(const f32x4*)&cs1[er0];
        #pragma unroll
        for (int fn = 0; fn < 2; ++fn) {
            int nl = fn*16 + l15;
            int gnn = n0 + nl; if (gnn > N_-1) gnn = N_-1;
            float g = gate[gnn*E_ + e];
            float m = meanS[nl];
            u16x4 pk;
            #pragma unroll
            for (int j = 0; j < 4; ++j)
                pk[j] = f2bf(g * (acc[fm][fn][j] - m * c4[j]));
            *(u16x4*)&hgb[(size_t)nl*KB2 + er0] = pk;
        }
    }
    {   // K-extension cols 256..287: 32 rows x 16 segs x 2 cols
        int nl = tid >> 4, sg = tid & 15;
        int gnn = n0 + nl; if (gnn > N_-1) gnn = N_-1;
        float sd = sdS[nl], m = meanS[nl];
        u16x2 pk;
        #pragma unroll
        for (int jj = 0; jj < 2; ++jj) {
            int k = sg*2 + jj;
            float vv = (k < E_) ? gate[gnn*E_ + k] * sd : ((k == E_) ? m : 0.f);
            pk[jj] = f2bf(vv);
        }
        *(u16x2*)&hgb[(size_t)nl*KB2 + ER_ + sg*2] = pk;
    }
}

// ---------------- GEMM2: out = w2x . hg^T, one LDS stage + barrier ----------
#define HGS 296
__global__ __launch_bounds__(512, 6) void gemm2_kernel(
        const unsigned short* __restrict__ hg, const unsigned short* __restrict__ w2x,
        float* __restrict__ out) {
    __shared__ __align__(16) char smem[64 * HGS * 2];      // 37888 B
    unsigned short* hgL = (unsigned short*)smem;
    const int bid = blockIdx.x;
    const int xcd = bid & 7;
    const int idx = bid >> 3;
    const int b   = (xcd << 3) + idx / 36;
    const int rem = idx % 36;
    const int p0  = (rem / 6) * 128;
    const int n0  = (rem % 6) * 64;

    const int tid  = threadIdx.x;
    const int lane = tid & 63;
    const int wave = tid >> 6;
    const int l15  = lane & 15;
    const int kgrp = lane >> 4;

    const unsigned short* hgb = hg + ((size_t)b * HGROWS + n0) * KB2;
    #pragma unroll
    for (int it = 0; it < 5; ++it) {
        int c = tid + it*512;
        if (c < 64*36) {
            int row = c / 36, col = c % 36;
            *(u16x8*)&hgL[(size_t)row*HGS + col*8] =
                *(const u16x8*)&hgb[(size_t)row*KB2 + col*8];
        }
    }
    __syncthreads();

    int prow = p0 + wave*16 + l15; if (prow > P_-1) prow = P_-1;
    const unsigned short* ap = w2x + (size_t)prow*KB2;
    f32x4 o[4];
    #pragma unroll
    for (int j = 0; j < 4; ++j) o[j] = (f32x4){0.f,0.f,0.f,0.f};
    #pragma unroll
    for (int ks = 0; ks < 9; ++ks) {
        bf16x8 afr = *(const bf16x8*)&ap[ks*32 + kgrp*8];
        #pragma unroll
        for (int fn = 0; fn < 4; ++fn) {
            bf16x8 bfr = *(const bf16x8*)&hgL[(size_t)(fn*16 + l15)*HGS + ks*32 + kgrp*8];
            o[fn] = __builtin_amdgcn_mfma_f32_16x16x32_bf16(afr, bfr, o[fn], 0, 0, 0);
        }
    }
    __syncthreads();

    float* patch = (float*)smem + wave * 1088;   // [16][68] f32
    #pragma unroll
    for (int fn = 0; fn < 4; ++fn)
        #pragma unroll
        for (int j = 0; j < 4; ++j)
            patch[(kgrp*4 + j)*68 + fn*16 + l15] = o[fn][j];
    const int pw0 = p0 + wave*16;
    #pragma unroll
    for (int pass = 0; pass < 4; ++pass) {
        int ploc = pass*4 + kgrp;
        f32x4 v = *(const f32x4*)&patch[ploc*68 + l15*4];
        int p = pw0 + ploc;
        int n = n0 + l15*4;
        if (p < P_) {
            float* orow = out + ((size_t)b*P_ + p)*N_;
            if (n + 3 < N_) {
                *(f32x4*)&orow[n] = v;
            } else {
                #pragma unroll
                for (int j = 0; j < 4; ++j)
                    if (n + j < N_) orow[n + j] = v[j];
            }
        }
    }
}

extern "C" void kernel_launch(void* const* d_in, const int* in_sizes, int n_in,
                              void* d_out, int out_size, void* d_ws, size_t ws_size,
                              hipStream_t stream) {
    const float* x     = (const float*)d_in[0];
    const float* ident = (const float*)d_in[1];
    const float* rw1   = (const float*)d_in[2];
    const float* rb1   = (const float*)d_in[3];
    const float* rw2   = (const float*)d_in[4];
    const float* rb2   = (const float*)d_in[5];
    const float* w1    = (const float*)d_in[6];
    const float* w2    = (const float*)d_in[7];
    const float* bias  = (const float*)d_in[8];
    float* out = (float*)d_out;
    float* ws  = (float*)d_ws;

    float* gate = ws + OFF_GATE;
    float* cs1  = ws + OFF_CS1;
    unsigned short* w1k = (unsigned short*)(ws + OFF_W1K);
    unsigned short* w2x = (unsigned short*)(ws + OFF_W2X);
    unsigned short* xT  = (unsigned short*)(ws + OFF_XT);
    unsigned short* hg  = (unsigned short*)(ws + OFF_HG);

    prep_kernel<<<856 + N_, 512, 0, stream>>>(w1, w2, bias, ident, rw1, rb1,
                                              rw2, rb2, w1k, w2x, cs1, gate);
    prepx2_kernel<<<512, 512, 0, stream>>>(x, xT);
    gemm1_kernel<<<dim3(704), 512, 0, stream>>>(xT, w1k, gate, cs1, hg);
    gemm2_kernel<<<dim3(2304), 512, 0, stream>>>(hg, w2x, out);
}

// Round 18
// 59.599 us; speedup vs baseline: 1.3404x; 1.3404x over previous
//
#include <hip/hip_runtime.h>
#include <math.h>

#define B_ 64
#define L_ 512
#define N_ 321
#define P_ 720
#define E_ 8
#define R_ 32
#define CID_ 32
#define H_ 64
#define ER_ 256
#define KB2 288      // ER_ + 8 bias-rank + 1 mean + 23 zero-pad
#define HGROWS 384   // 6 n-tiles x 64 (rows >= N_ hold dup/junk, never used)

typedef __attribute__((ext_vector_type(8))) short bf16x8;
typedef __attribute__((ext_vector_type(4))) float f32x4;
typedef __attribute__((ext_vector_type(8))) unsigned short u16x8;
typedef __attribute__((ext_vector_type(4))) unsigned short u16x4;

// workspace layout (float offsets)
#define OFF_GATE 0                        // 2568
#define OFF_CS1  2568                     // 256
#define OFF_W1K  2824                     // bf16 256*512 = 65536 f
#define OFF_W2X  68360                    // bf16 720*288 = 103680 f
#define OFF_HG   172040                   // bf16 64*384*288 = 3538944 f
// total ~14.8 MB

__device__ __forceinline__ unsigned short f2bf(float f) {
    unsigned u = __float_as_uint(f);
    u += 0x7fffu + ((u >> 16) & 1u);
    return (unsigned short)(u >> 16);
}
__device__ __forceinline__ float bf2f(unsigned short h) {
    return __uint_as_float(((unsigned)h) << 16);
}

// ---------------- prep: w1k, w2x, cs1, router (merged) ----------------------
__global__ void prep_kernel(const float* __restrict__ w1, const float* __restrict__ w2,
                            const float* __restrict__ bias,
                            const float* __restrict__ ident,
                            const float* __restrict__ rw1, const float* __restrict__ rb1,
                            const float* __restrict__ rw2, const float* __restrict__ rb2,
                            unsigned short* __restrict__ w1k, unsigned short* __restrict__ w2x,
                            float* __restrict__ cs1, float* __restrict__ gate) {
    __shared__ float red[16][32];
    __shared__ float hid[H_];
    __shared__ float lg[E_];
    int bid = blockIdx.x, t = threadIdx.x;
    if (bid < 128) {                  // w1k [er][l]: 256*512 elems, 512 thr x 2
        #pragma unroll
        for (int r = 0; r < 2; ++r) {
            int g = bid*1024 + r*512 + t;
            int er = g >> 9, l = g & 511;
            w1k[g] = f2bf(w1[(size_t)(er >> 5)*(L_*R_) + (size_t)l*R_ + (er & 31)]);
        }
    } else if (bid < 848) {           // w2x row p: K-extended
        int p = bid - 128;
        if (t < KB2) {
            unsigned short v;
            if (t < ER_)            v = f2bf(w2[(size_t)t*P_ + p]);
            else if (t < ER_ + E_)  v = f2bf(bias[(size_t)(t - ER_)*P_ + p]);
            else if (t == ER_ + E_) v = 0x3f80;  // bf16(1.0) for the mean lane
            else                    v = 0;
            w2x[(size_t)p*KB2 + t] = v;
        }
    } else if (bid < 856) {           // cs1: 8 blocks, one expert each (512 thr)
        int e = bid - 848;
        int q = t >> 5, r = t & 31;
        float s = 0.f;
        for (int l = q; l < L_; l += 16)
            s += bf2f(f2bf(w1[(size_t)e*(L_*R_) + (size_t)l*R_ + r]));
        red[q][r] = s;
        __syncthreads();
        if (q == 0) {
            #pragma unroll
            for (int qq = 1; qq < 16; ++qq) s += red[qq][r];
            cs1[e*32 + r] = s;
        }
    } else {                          // router: one n per block (t<64 active)
        int n = bid - 856;
        if (t < H_) {
            float acc = rb1[t];
            #pragma unroll
            for (int c = 0; c < CID_; ++c)
                acc = fmaf(ident[n*CID_ + c], rw1[c*H_ + t], acc);
            hid[t] = fmaxf(acc, 0.f);
        }
        __syncthreads();
        if (t < E_) {
            float a = rb2[t];
            #pragma unroll
            for (int h = 0; h < H_; ++h) a = fmaf(hid[h], rw2[h*E_ + t], a);
            lg[t] = a;
        }
        __syncthreads();
        if (t == 0) {
            float m = lg[0];
            #pragma unroll
            for (int e = 1; e < E_; ++e) m = fmaxf(m, lg[e]);
            float s = 0.f, ex[E_];
            #pragma unroll
            for (int e = 0; e < E_; ++e) { ex[e] = expf(lg[e] - m); s += ex[e]; }
            float inv = 1.f / s;
            #pragma unroll
            for (int e = 0; e < E_; ++e) gate[n*E_ + e] = ex[e] * inv;
        }
    }
}

// ---------------- GEMM1: er-half split, VGPR headroom (512,4) ---------------
// grid 768 = 8 xcd * (8 b * 6 nt * 2 eq), 512 thr. Wave owns 16er x 64n;
// 4-round K=128 ping-pong; fused f32 stats; epilogue gate*(acc - mean*cs1);
// K-ext written by eq==1. launch_bounds(512,4): ~128 VGPR so the 16 staging
// loads + 4-slot A-ring stay fully in flight (R16's (512,6) squeezed to 40
// VGPR and serialized the load pipeline).
__global__ __launch_bounds__(512, 4) void gemm1_kernel(
        const float* __restrict__ x, const unsigned short* __restrict__ w1k,
        const float* __restrict__ gate, const float* __restrict__ cs1,
        unsigned short* __restrict__ hg) {
    __shared__ unsigned short buf[2][64][128];   // 32768 B, XOR-swizzled rows
    __shared__ float red1[8][64], red2[8][64];   // 4096 B
    __shared__ float meanS[64], sdS[64];

    const int bid = blockIdx.x;
    const int xcd = bid & 7;
    const int idx = bid >> 3;            // 0..95
    const int b   = (xcd << 3) + idx / 12;
    const int rem = idx % 12;
    const int nt  = rem >> 1;            // 0..5
    const int eq  = rem & 1;             // er-half
    const int n0  = nt * 64;
    const int m0  = eq * 128;

    const int tid  = threadIdx.x;
    const int lane = tid & 63;
    const int wave = tid >> 6;          // 0..7
    const int l15  = lane & 15;
    const int kgrp = lane >> 4;         // 0..3

    // staging role: thread = (xn, wave): 16 k per round, lanes coalesced on n
    const int xn  = lane;
    const int gn  = n0 + xn;
    const int gnc = (gn < N_) ? gn : (N_ - 1);
    const float* xp = x + (size_t)b*L_*N_ + gnc;
    const int swz = (xn & 7) << 4;       // byte-XOR for LDS row xn
    char* myrow0 = (char*)&buf[0][xn][0];
    char* myrow1 = (char*)&buf[1][xn][0];

    // MFMA roles: wave owns er rows m0 + wave*16 .. +16
    const unsigned short* apA = w1k + (size_t)(m0 + wave*16 + l15)*L_;
    const int rsw = (l15 & 7) << 4;

    float s1 = 0.f, s2 = 0.f;
    float v[16];
    f32x4 acc[4];
    #pragma unroll
    for (int j = 0; j < 4; ++j) acc[j] = (f32x4){0.f,0.f,0.f,0.f};

#define LOADV(rd_) {                                                            \
    const int kb = (rd_)*128 + wave*16;                                         \
    _Pragma("unroll")                                                           \
    for (int i_ = 0; i_ < 16; ++i_)                                             \
        v[i_] = xp[(size_t)(kb + i_)*N_]; }
#define STOREV(rd_) {                                                           \
    char* dst = ((rd_) & 1) ? myrow1 : myrow0;                                  \
    u16x8 pk0, pk1;                                                             \
    _Pragma("unroll")                                                           \
    for (int i_ = 0; i_ < 8; ++i_) {                                            \
        s1 += v[i_]; s2 = fmaf(v[i_], v[i_], s2); pk0[i_] = f2bf(v[i_]); }      \
    _Pragma("unroll")                                                           \
    for (int i_ = 0; i_ < 8; ++i_) {                                            \
        float f_ = v[8+i_];                                                     \
        s1 += f_; s2 = fmaf(f_, f_, s2); pk1[i_] = f2bf(f_); }                  \
    *(u16x8*)(dst + ((wave*32)      ^ swz)) = pk0;                              \
    *(u16x8*)(dst + ((wave*32 + 16) ^ swz)) = pk1; }

    LOADV(0);
    STOREV(0);
    __syncthreads();

    // A-fragment ring: 4 slots, prefetch distance 2
    bf16x8 af[4];
#define LDA(s_, kk_) af[s_] = *(const bf16x8*)&apA[(kk_)*32 + kgrp*8];
    LDA(0, 0); LDA(1, 1);

    #pragma unroll
    for (int rd = 0; rd < 4; ++rd) {
        if (rd < 3) LOADV(rd + 1);          // global loads hide under MFMA
        const unsigned short (*cb)[128] = buf[rd & 1];
        #pragma unroll
        for (int ks = 0; ks < 4; ++ks) {
            const int kk = rd*4 + ks;
            if (kk + 2 < 16) LDA((kk + 2) & 3, kk + 2);
            const int cbyte = ks*64 + kgrp*16;
            bf16x8 bfr[4];
            #pragma unroll
            for (int fn = 0; fn < 4; ++fn)
                bfr[fn] = *(const bf16x8*)((const char*)&cb[fn*16 + l15][0] + (cbyte ^ rsw));
            #pragma unroll
            for (int fn = 0; fn < 4; ++fn)
                acc[fn] = __builtin_amdgcn_mfma_f32_16x16x32_bf16(af[kk & 3], bfr[fn], acc[fn], 0, 0, 0);
        }
        if (rd < 3) STOREV(rd + 1);
        __syncthreads();
    }
#undef LDA
#undef LOADV
#undef STOREV

    // ---- stats reduce (f32-exact; accumulated during staging) ----
    red1[wave][xn] = s1;
    red2[wave][xn] = s2;
    __syncthreads();
    if (tid < 64) {
        float a = 0.f, qq = 0.f;
        #pragma unroll
        for (int kk = 0; kk < 8; ++kk) { a += red1[kk][tid]; qq += red2[kk][tid]; }
        float mean = a * (1.f/L_);
        float var = (qq - (float)L_*mean*mean) * (1.f/(L_-1));
        var = fmaxf(var, 0.f);
        meanS[tid] = mean;
        sdS[tid]   = sqrtf(var) + 1e-6f;
    }
    __syncthreads();

    // ---- epilogue: hg[b][n0+nl][m0..m0+128) = gate*(acc - mean*cs1) ----
    unsigned short* hgb = hg + ((size_t)b * HGROWS + n0) * KB2;
    {
        int er0 = m0 + wave*16 + kgrp*4;
        int e = er0 >> 5;
        f32x4 c4 = *(const f32x4*)&cs1[er0];
        #pragma unroll
        for (int fn = 0; fn < 4; ++fn) {
            int nl = fn*16 + l15;
            int gnn = n0 + nl; if (gnn > N_-1) gnn = N_-1;
            float g = gate[gnn*E_ + e];
            float m = meanS[nl];
            u16x4 pk;
            #pragma unroll
            for (int j = 0; j < 4; ++j)
                pk[j] = f2bf(g * (acc[fn][j] - m * c4[j]));
            *(u16x4*)&hgb[(size_t)nl*KB2 + er0] = pk;
        }
    }
    if (eq == 1) {   // K-extension cols 256..287: 64 rows x 8 segs (512 thr)
        int nl = tid >> 3, seg = tid & 7;
        int gnn = n0 + nl; if (gnn > N_-1) gnn = N_-1;
        float sd = sdS[nl], m = meanS[nl];
        u16x4 pk;
        #pragma unroll
        for (int jj = 0; jj < 4; ++jj) {
            int k = seg*4 + jj;
            float vv = (k < E_) ? gate[gnn*E_ + k] * sd : ((k == E_) ? m : 0.f);
            pk[jj] = f2bf(vv);
        }
        *(u16x4*)&hgb[(size_t)nl*KB2 + ER_ + seg*4] = pk;
    }
}

// ---------------- GEMM2: out = w2x . hg^T, one LDS stage + barrier ----------
// grid 2304 = 8 xcd * (8 b * (6 pt * 6 nt)); BM=128 p, BN=64 n, K=288.
#define HGS 296   // u16 LDS stride (148 dw -> 2-way aliasing, free)
__global__ __launch_bounds__(512, 6) void gemm2_kernel(
        const unsigned short* __restrict__ hg, const unsigned short* __restrict__ w2x,
        float* __restrict__ out) {
    __shared__ __align__(16) char smem[64 * HGS * 2];      // 37888 B
    unsigned short* hgL = (unsigned short*)smem;           // [64][296]
    const int bid = blockIdx.x;
    const int xcd = bid & 7;
    const int idx = bid >> 3;            // 0..287
    const int b   = (xcd << 3) + idx / 36;
    const int rem = idx % 36;
    const int p0  = (rem / 6) * 128;
    const int n0  = (rem % 6) * 64;

    const int tid  = threadIdx.x;
    const int lane = tid & 63;
    const int wave = tid >> 6;
    const int l15  = lane & 15;
    const int kgrp = lane >> 4;

    // stage hg tile [64][288] -> LDS (16B chunks, 36 per row)
    const unsigned short* hgb = hg + ((size_t)b * HGROWS + n0) * KB2;
    #pragma unroll
    for (int it = 0; it < 5; ++it) {
        int c = tid + it*512;
        if (c < 64*36) {
            int row = c / 36, col = c % 36;
            *(u16x8*)&hgL[(size_t)row*HGS + col*8] =
                *(const u16x8*)&hgb[(size_t)row*KB2 + col*8];
        }
    }
    __syncthreads();

    // K-loop: wave owns 16 p-rows; A-frags from L2-hot w2x, B-frags from LDS
    int prow = p0 + wave*16 + l15; if (prow > P_-1) prow = P_-1;
    const unsigned short* ap = w2x + (size_t)prow*KB2;
    f32x4 o[4];
    #pragma unroll
    for (int j = 0; j < 4; ++j) o[j] = (f32x4){0.f,0.f,0.f,0.f};
    #pragma unroll
    for (int ks = 0; ks < 9; ++ks) {
        bf16x8 afr = *(const bf16x8*)&ap[ks*32 + kgrp*8];
        #pragma unroll
        for (int fn = 0; fn < 4; ++fn) {
            bf16x8 bfr = *(const bf16x8*)&hgL[(size_t)(fn*16 + l15)*HGS + ks*32 + kgrp*8];
            o[fn] = __builtin_amdgcn_mfma_f32_16x16x32_bf16(afr, bfr, o[fn], 0, 0, 0);
        }
    }
    __syncthreads();   // all waves done reading hgL; patch may overwrite

    // patch-transpose: D rows p_loc = kgrp*4+j, cols n_loc = fn*16+l15
    float* patch = (float*)smem + wave * 1088;   // [16][68] f32 = 4352 B
    #pragma unroll
    for (int fn = 0; fn < 4; ++fn)
        #pragma unroll
        for (int j = 0; j < 4; ++j)
            patch[(kgrp*4 + j)*68 + fn*16 + l15] = o[fn][j];
    const int pw0 = p0 + wave*16;
    #pragma unroll
    for (int pass = 0; pass < 4; ++pass) {
        int ploc = pass*4 + kgrp;
        f32x4 v = *(const f32x4*)&patch[ploc*68 + l15*4];
        int p = pw0 + ploc;
        int n = n0 + l15*4;
        if (p < P_) {
            float* orow = out + ((size_t)b*P_ + p)*N_;
            if (n + 3 < N_) {
                *(f32x4*)&orow[n] = v;
            } else {
                #pragma unroll
                for (int j = 0; j < 4; ++j)
                    if (n + j < N_) orow[n + j] = v[j];
            }
        }
    }
}

extern "C" void kernel_launch(void* const* d_in, const int* in_sizes, int n_in,
                              void* d_out, int out_size, void* d_ws, size_t ws_size,
                              hipStream_t stream) {
    const float* x     = (const float*)d_in[0];
    const float* ident = (const float*)d_in[1];
    const float* rw1   = (const float*)d_in[2];
    const float* rb1   = (const float*)d_in[3];
    const float* rw2   = (const float*)d_in[4];
    const float* rb2   = (const float*)d_in[5];
    const float* w1    = (const float*)d_in[6];
    const float* w2    = (const float*)d_in[7];
    const float* bias  = (const float*)d_in[8];
    float* out = (float*)d_out;
    float* ws  = (float*)d_ws;

    float* gate = ws + OFF_GATE;
    float* cs1  = ws + OFF_CS1;
    unsigned short* w1k = (unsigned short*)(ws + OFF_W1K);
    unsigned short* w2x = (unsigned short*)(ws + OFF_W2X);
    unsigned short* hg  = (unsigned short*)(ws + OFF_HG);

    prep_kernel<<<856 + N_, 512, 0, stream>>>(w1, w2, bias, ident, rw1, rb1,
                                              rw2, rb2, w1k, w2x, cs1, gate);
    gemm1_kernel<<<dim3(768), 512, 0, stream>>>(x, w1k, gate, cs1, hg);
    gemm2_kernel<<<dim3(2304), 512, 0, stream>>>(hg, w2x, out);
}